// Round 2
// baseline (353.487 us; speedup 1.0000x reference)
//
#include <hip/hip_runtime.h>
#include <math.h>

#define HH 64

// ---------------- init ----------------

__global__ void k_init(int* __restrict__ head, int* __restrict__ cnt,
                       float* __restrict__ sums, int* __restrict__ cursor,
                       int n, int pn) {
    int i = blockIdx.x * blockDim.x + threadIdx.x;
    if (i < n) { head[i] = -1; cnt[i] = 0; }
    if (i < pn) sums[i] = 0.f;
    if (i == 0) *cursor = 0;
}

// ---------------- CSR build pass 1: link + degree count (coalesced writes) ----
// next[e] writes are coalesced (e sequential). head/cnt atomics hit a 200 KB
// L2-resident region. cnt atomicAdd is fire-and-forget (no return use).
__global__ void k_link_count(const int* __restrict__ col, int E,
                             int* __restrict__ head, int* __restrict__ next,
                             int* __restrict__ cnt) {
    int e = blockIdx.x * blockDim.x + threadIdx.x;
    if (e >= E) return;
    int c = col[e];
    atomicAdd(&cnt[c], 1);
    int prev = atomicExch(&head[c], e);
    next[e] = prev;
}

// ---------------- CSR build pass 2: prefix alloc + SINGLE list walk ----------
// Degree is known from cnt, so only ONE dependent-chain traversal is needed
// (round-0's fused kernel walked twice at 15.7% occupancy; this kernel has
// no LDS and tiny VGPR use -> full occupancy, all 50k chains concurrent).
// Per-node csr writes are contiguous (dst++) -> no write amplification.
__global__ __launch_bounds__(256) void k_alloc_walk(const int* __restrict__ cnt,
                                                    const int* __restrict__ head,
                                                    const int* __restrict__ next,
                                                    const int* __restrict__ row,
                                                    int* __restrict__ cursor,
                                                    int* __restrict__ rowptr,
                                                    float* __restrict__ dinv,
                                                    int* __restrict__ csr, int n) {
    int node = blockIdx.x * blockDim.x + threadIdx.x;
    int lane = threadIdx.x & 63;
    if (node - lane >= n) return;           // whole wave out of range
    int len = (node < n) ? cnt[node] : 0;
    if (node < n) dinv[node] = rsqrtf((float)(len + 1));
    int incl = len;
#pragma unroll
    for (int off = 1; off < 64; off <<= 1) {
        int t = __shfl_up(incl, off, 64);
        if (lane >= off) incl += t;
    }
    int total = __shfl(incl, 63, 64);
    int base = 0;
    if (lane == 0 && total > 0) base = atomicAdd(cursor, total);
    base = __shfl(base, 0, 64);
    int dst = base + incl - len;
    if (node < n) {
        rowptr[node] = dst;
        for (int p = head[node]; p >= 0; p = next[p]) csr[dst++] = row[p];
    }
}

// ---------------- dense transform: 64-node tile, optional dinv pre-scale ----------------
// FIN=128 LDS = 128*64*4 + 32*68*4 = 41472 B -> 3 blocks/CU max; FIN=64 -> 4.
template<int FIN, bool SCALE>
__global__ __launch_bounds__(256, (FIN == 128) ? 3 : 4)
void k_gemm(const float* __restrict__ x, const float* __restrict__ W,
            const float* __restrict__ dinv, float* __restrict__ out, int n) {
    constexpr int KC = 32;
    constexpr int XS = 68;
    __shared__ __align__(16) float Ws[FIN][HH];
    __shared__ __align__(16) float xs_t[KC][XS];
    const int tid = threadIdx.x;
    const int tx = tid & 15;
    const int ty = tid >> 4;
    const int node0 = blockIdx.x * 64;
    if (node0 >= n) return;

    for (int i = tid * 4; i < FIN * HH; i += 1024)
        *(float4*)&Ws[0][i] = *(const float4*)&W[i];

    float acc[4][4] = {};
    const int rr0 = tid >> 3;
    const int cc  = (tid & 7) * 4;

    for (int kc = 0; kc < FIN; kc += KC) {
        __syncthreads();
        for (int rr = rr0; rr < 64; rr += 32) {
            float4 v = make_float4(0.f, 0.f, 0.f, 0.f);
            if (node0 + rr < n) v = *(const float4*)&x[(size_t)(node0 + rr) * FIN + kc + cc];
            xs_t[cc + 0][rr] = v.x;
            xs_t[cc + 1][rr] = v.y;
            xs_t[cc + 2][rr] = v.z;
            xs_t[cc + 3][rr] = v.w;
        }
        __syncthreads();
#pragma unroll 4
        for (int k = 0; k < KC; ++k) {
            float4 a4 = *(const float4*)&xs_t[k][ty * 4];
            float4 b4 = *(const float4*)&Ws[kc + k][tx * 4];
            acc[0][0] = fmaf(a4.x, b4.x, acc[0][0]);
            acc[0][1] = fmaf(a4.x, b4.y, acc[0][1]);
            acc[0][2] = fmaf(a4.x, b4.z, acc[0][2]);
            acc[0][3] = fmaf(a4.x, b4.w, acc[0][3]);
            acc[1][0] = fmaf(a4.y, b4.x, acc[1][0]);
            acc[1][1] = fmaf(a4.y, b4.y, acc[1][1]);
            acc[1][2] = fmaf(a4.y, b4.z, acc[1][2]);
            acc[1][3] = fmaf(a4.y, b4.w, acc[1][3]);
            acc[2][0] = fmaf(a4.z, b4.x, acc[2][0]);
            acc[2][1] = fmaf(a4.z, b4.y, acc[2][1]);
            acc[2][2] = fmaf(a4.z, b4.z, acc[2][2]);
            acc[2][3] = fmaf(a4.z, b4.w, acc[2][3]);
            acc[3][0] = fmaf(a4.w, b4.x, acc[3][0]);
            acc[3][1] = fmaf(a4.w, b4.y, acc[3][1]);
            acc[3][2] = fmaf(a4.w, b4.z, acc[3][2]);
            acc[3][3] = fmaf(a4.w, b4.w, acc[3][3]);
        }
    }

#pragma unroll
    for (int i = 0; i < 4; ++i) {
        int node = node0 + ty * 4 + i;
        if (node < n) {
            if (SCALE) {
                float d = dinv[node];
                float4 o = make_float4(acc[i][0] * d, acc[i][1] * d,
                                       acc[i][2] * d, acc[i][3] * d);
                *(float4*)&out[(size_t)node * HH + tx * 4] = o;
            } else {
                *(float4*)&out[(size_t)node * HH + tx * 4] = *(float4*)acc[i];
            }
        }
    }
}

// ---------------- gather: quarter-wave float4 (R17-verified structure) ----------------
// WEIGHTED (layer 1): lin unscaled, per-edge weight dinv[src], self weight di.
// else (layers 2-3): linS pre-scaled, weight 1, self weight 1.
// All cross-lane shfls UNCONDITIONAL (uniform exec — the R14 lesson); range
// guards live in wv only. Source lane j+q*4+t <= 63, no wrap needed.
template<bool WEIGHTED>
__global__ __launch_bounds__(256) void k_gather_q(const float* __restrict__ lin,
                                                  const int* __restrict__ csr,
                                                  const int* __restrict__ rowptr,
                                                  const int* __restrict__ cnt,
                                                  const float* __restrict__ dinv,
                                                  const float* __restrict__ b,
                                                  float* __restrict__ hout, int n) {
    int node = blockIdx.x * 4 + (threadIdx.x >> 6);
    int lane = threadIdx.x & 63;
    if (node >= n) return;
    const int q  = lane >> 4;          // quarter 0..3
    const int fl = (lane & 15) * 4;    // float4 feature offset
    int start = rowptr[node];
    int end = start + cnt[node];
    float di = dinv[node];

    float4 a0 = make_float4(0.f, 0.f, 0.f, 0.f);
    float4 a1 = make_float4(0.f, 0.f, 0.f, 0.f);

    for (int base = start; base < end; base += 64) {
        int m = end - base; if (m > 64) m = 64;
        int idx = base + lane;
        int   sv = (idx < end) ? csr[idx] : 0;
        float wv;
        if (WEIGHTED) wv = (idx < end) ? dinv[sv] : 0.f;   // predicated load: safe
        else          wv = (idx < end) ? 1.f : 0.f;
        for (int j = 0; j < m; j += 16) {
            int l = j + q * 4;                       // <= 63 always
            int   s0 = __shfl(sv, l, 64);            // unconditional, uniform
            int   s1 = __shfl(sv, l + 1, 64);
            int   s2 = __shfl(sv, l + 2, 64);
            int   s3 = __shfl(sv, l + 3, 64);
            float w0 = __shfl(wv, l, 64);
            float w1 = __shfl(wv, l + 1, 64);
            float w2 = __shfl(wv, l + 2, 64);
            float w3 = __shfl(wv, l + 3, 64);
            float4 v0 = *(const float4*)&lin[(size_t)s0 * HH + fl];
            float4 v1 = *(const float4*)&lin[(size_t)s1 * HH + fl];
            float4 v2 = *(const float4*)&lin[(size_t)s2 * HH + fl];
            float4 v3 = *(const float4*)&lin[(size_t)s3 * HH + fl];
            a0.x = fmaf(w0, v0.x, a0.x); a0.y = fmaf(w0, v0.y, a0.y);
            a0.z = fmaf(w0, v0.z, a0.z); a0.w = fmaf(w0, v0.w, a0.w);
            a1.x = fmaf(w1, v1.x, a1.x); a1.y = fmaf(w1, v1.y, a1.y);
            a1.z = fmaf(w1, v1.z, a1.z); a1.w = fmaf(w1, v1.w, a1.w);
            a0.x = fmaf(w2, v2.x, a0.x); a0.y = fmaf(w2, v2.y, a0.y);
            a0.z = fmaf(w2, v2.z, a0.z); a0.w = fmaf(w2, v2.w, a0.w);
            a1.x = fmaf(w3, v3.x, a1.x); a1.y = fmaf(w3, v3.y, a1.y);
            a1.z = fmaf(w3, v3.z, a1.z); a1.w = fmaf(w3, v3.w, a1.w);
        }
    }
    float4 acc = make_float4(a0.x + a1.x, a0.y + a1.y, a0.z + a1.z, a0.w + a1.w);
#pragma unroll
    for (int off = 16; off < 64; off <<= 1) {
        acc.x += __shfl_xor(acc.x, off, 64);
        acc.y += __shfl_xor(acc.y, off, 64);
        acc.z += __shfl_xor(acc.z, off, 64);
        acc.w += __shfl_xor(acc.w, off, 64);
    }
    // self-loop term: weight di (weighted) or 1 (pre-scaled input)
    float4 self = *(const float4*)&lin[(size_t)node * HH + fl];
    float sw = WEIGHTED ? di : 1.f;
    acc.x = fmaf(sw, self.x, acc.x);
    acc.y = fmaf(sw, self.y, acc.y);
    acc.z = fmaf(sw, self.z, acc.z);
    acc.w = fmaf(sw, self.w, acc.w);
    // bias + L2 norm + relu
    float4 b4 = *(const float4*)&b[fl];
    float4 v4 = make_float4(fmaf(di, acc.x, b4.x), fmaf(di, acc.y, b4.y),
                            fmaf(di, acc.z, b4.z), fmaf(di, acc.w, b4.w));
    float ss = v4.x * v4.x + v4.y * v4.y + v4.z * v4.z + v4.w * v4.w;
#pragma unroll
    for (int off = 1; off < 16; off <<= 1) ss += __shfl_xor(ss, off, 64);
    float inv = 1.f / fmaxf(sqrtf(ss), 1e-12f);
    v4.x = fmaxf(v4.x * inv, 0.f);
    v4.y = fmaxf(v4.y * inv, 0.f);
    v4.z = fmaxf(v4.z * inv, 0.f);
    v4.w = fmaxf(v4.w * inv, 0.f);
    if (q == 0) *(float4*)&hout[(size_t)node * HH + fl] = v4;
}

// ---------------- pooling ----------------
__global__ __launch_bounds__(256) void k_pool(const float* __restrict__ node_emb,
                                              const int* __restrict__ batch,
                                              float* __restrict__ sums,
                                              float* __restrict__ cnts, int n) {
    const int NPW = 16;
    int wave = blockIdx.x * 4 + (threadIdx.x >> 6);
    int lane = threadIdx.x & 63;
    int start = wave * NPW;
    if (start >= n) return;
    int end = start + NPW; if (end > n) end = n;
    int cur = batch[start];
    float acc = 0.f;
    int runlen = 0;
    for (int node = start; node < end; ++node) {
        int g = batch[node];
        if (g != cur) {
            atomicAdd(&sums[(size_t)cur * HH + lane], acc);
            if (lane == 0) atomicAdd(&cnts[cur], (float)runlen);
            acc = 0.f; runlen = 0; cur = g;
        }
        acc += node_emb[(size_t)node * HH + lane];
        ++runlen;
    }
    atomicAdd(&sums[(size_t)cur * HH + lane], acc);
    if (lane == 0) atomicAdd(&cnts[cur], (float)runlen);
}

// ---------------- classifier + softmax ----------------
__global__ void k_final2(const float* __restrict__ sums, const float* __restrict__ cnts,
                         const float* __restrict__ Wm, const float* __restrict__ bm,
                         float* __restrict__ logits, float* __restrict__ probs,
                         float* __restrict__ graph_emb) {
    int g = blockIdx.x;
    int lane = threadIdx.x;
    float mean = sums[(size_t)g * HH + lane] / fmaxf(cnts[g], 1.0f);
    graph_emb[(size_t)g * HH + lane] = mean;

    __shared__ float semb[HH];
    __shared__ float slog[16];
    semb[lane] = mean;
    __syncthreads();
    if (lane < 10) {
        float acc = bm[lane];
        for (int k = 0; k < HH; ++k) acc = fmaf(semb[k], Wm[k * 10 + lane], acc);
        slog[lane] = acc;
    }
    __syncthreads();
    if (lane < 10) {
        float mx = -1e30f;
        for (int j = 0; j < 10; ++j) mx = fmaxf(mx, slog[j]);
        float den = 0.f;
        for (int j = 0; j < 10; ++j) den += __expf(slog[j] - mx);
        float lg = slog[lane];
        logits[g * 10 + lane] = lg;
        probs[g * 10 + lane] = __expf(lg - mx) / den;
    }
}

// ---------------- launch ----------------

extern "C" void kernel_launch(void* const* d_in, const int* in_sizes, int n_in,
                              void* d_out, int out_size, void* d_ws, size_t ws_size,
                              hipStream_t stream) {
    const float* x     = (const float*)d_in[0];
    const int*   ei    = (const int*)  d_in[1];
    const int*   batch = (const int*)  d_in[2];
    const float* W1 = (const float*)d_in[3];  const float* b1 = (const float*)d_in[4];
    const float* W2 = (const float*)d_in[5];  const float* b2 = (const float*)d_in[6];
    const float* W3 = (const float*)d_in[7];  const float* b3 = (const float*)d_in[8];
    const float* Wm = (const float*)d_in[9];  const float* bm = (const float*)d_in[10];

    const int N = in_sizes[2];
    const int E = in_sizes[1] / 2;
    const int G = (out_size - N * HH) / (2 * 10 + HH);

    const int* row = ei;
    const int* col = ei + E;

    float* out       = (float*)d_out;
    float* logits    = out;
    float* probs     = out + (size_t)G * 10;
    float* node_emb  = out + (size_t)2 * G * 10;
    float* graph_emb = node_emb + (size_t)N * HH;

    char* w = (char*)d_ws;
    auto alloc = [&](size_t bytes) { char* p = w; w += (bytes + 255) & ~(size_t)255; return p; };
    float* dinv    = (float*)alloc((size_t)N * 4);
    int*   cnt     = (int*)  alloc((size_t)N * 4);
    int*   rowptr  = (int*)  alloc((size_t)N * 4);
    int*   head    = (int*)  alloc((size_t)N * 4);
    int*   nxt     = (int*)  alloc((size_t)E * 4);
    int*   cursor  = (int*)  alloc(256);
    float* sums    = (float*)alloc((size_t)G * HH * 4 + (size_t)G * 4);
    float* cnts    = sums + (size_t)G * HH;
    int*   csr     = (int*)  alloc((size_t)E * 4);
    float* bufA    = (float*)alloc((size_t)N * HH * 4);
    float* bufB    = (float*)alloc((size_t)N * HH * 4);

    const int B = 256;
    dim3 blk(B);
    int node_blocks = (N + 3) / 4;
    int gemm_blocks = (N + 63) / 64;
    int nB = (N + B - 1) / B;
    int eB = (E + B - 1) / B;
    int poolN = G * HH + G;
    int pool_blocks = (N + 63) / 64;

    // CSR build: init -> link+count (coalesced) -> alloc+single-walk (full occupancy)
    k_init<<<nB, blk, 0, stream>>>(head, cnt, sums, cursor, N, poolN);
    k_link_count<<<eB, blk, 0, stream>>>(col, E, head, nxt, cnt);
    k_alloc_walk<<<nB, blk, 0, stream>>>(cnt, head, nxt, row, cursor, rowptr, dinv, csr, N);

    // layer 1: dense transform (unscaled) + weighted quarter-wave gather
    k_gemm<128, false><<<gemm_blocks, blk, 0, stream>>>(x, W1, dinv, bufA, N);
    k_gather_q<true><<<node_blocks, blk, 0, stream>>>(bufA, csr, rowptr, cnt, dinv, b1, bufB, N);
    // layer 2: prescaled gemm + quarter-wave gather (bufB -> bufA -> bufB = h2)
    k_gemm<64, true><<<gemm_blocks, blk, 0, stream>>>(bufB, W2, dinv, bufA, N);
    k_gather_q<false><<<node_blocks, blk, 0, stream>>>(bufA, csr, rowptr, cnt, dinv, b2, bufB, N);
    // layer 3: prescaled gemm + quarter-wave gather (bufB -> bufA -> node_emb)
    k_gemm<64, true><<<gemm_blocks, blk, 0, stream>>>(bufB, W3, dinv, bufA, N);
    k_gather_q<false><<<node_blocks, blk, 0, stream>>>(bufA, csr, rowptr, cnt, dinv, b3, node_emb, N);

    // pool + classifier
    k_pool<<<pool_blocks, blk, 0, stream>>>(node_emb, batch, sums, cnts, N);
    k_final2<<<G, dim3(64), 0, stream>>>(sums, cnts, Wm, bm, logits, probs, graph_emb);
}

// Round 3
// 283.901 us; speedup vs baseline: 1.2451x; 1.2451x over previous
//
#include <hip/hip_runtime.h>
#include <math.h>

#define HH 64
// Bucket = col >> 8 (256 nodes per bucket). Assumes N <= 65536 (N=50000 here).
#define BSH 8
#define BSZ 256

// ---------------- init ----------------

__global__ void k_init(int* __restrict__ bucket_cnt, float* __restrict__ sums,
                       int nb, int pn) {
    int i = blockIdx.x * blockDim.x + threadIdx.x;
    if (i < nb) bucket_cnt[i] = 0;
    if (i < pn) sums[i] = 0.f;
}

// ---------------- CSR pass A: bucket histogram via LDS (no per-edge global atomics) ----
__global__ __launch_bounds__(256) void k_bhist(const int* __restrict__ col, int E,
                                               int* __restrict__ bucket_cnt, int nb) {
    __shared__ int h[BSZ];
    int t = threadIdx.x;
    h[t] = 0;
    __syncthreads();
    int stride = gridDim.x * blockDim.x;
    for (int e = blockIdx.x * blockDim.x + t; e < E; e += stride)
        atomicAdd(&h[col[e] >> BSH], 1);
    __syncthreads();
    if (t < nb && h[t]) atomicAdd(&bucket_cnt[t], h[t]);
}

// ---------------- CSR pass B: exclusive scan of bucket counts (single block) ----
__global__ __launch_bounds__(256) void k_bscan(const int* __restrict__ bc,
                                               int* __restrict__ base,
                                               int* __restrict__ cursor, int nb) {
    __shared__ int s[256];
    __shared__ int carry_s;
    int t = threadIdx.x;
    if (t == 0) carry_s = 0;
    __syncthreads();
    for (int off = 0; off < nb; off += 256) {
        int i = off + t;
        int v = (i < nb) ? bc[i] : 0;
        s[t] = v;
        __syncthreads();
        for (int d = 1; d < 256; d <<= 1) {
            int x = s[t];
            if (t >= d) x += s[t - d];
            __syncthreads();
            s[t] = x;
            __syncthreads();
        }
        int carry = carry_s;
        int excl = carry + s[t] - v;
        if (i < nb) { base[i] = excl; cursor[i] = excl; }
        int tot = s[255];
        __syncthreads();
        if (t == 0) carry_s = carry + tot;
        __syncthreads();
    }
    if (t == 0) base[nb] = carry_s;
}

// ---------------- CSR pass C: scatter edges into bucket-contiguous pair list ----
// One global atomic per (block,bucket) reservation (~50k total), per-edge order
// via LDS cursors. Each block's run per bucket is ~16 int2 contiguous -> stores
// merge into full cachelines (no write amplification).
__global__ __launch_bounds__(256) void k_bscatter(const int* __restrict__ row,
                                                  const int* __restrict__ col, int E,
                                                  int* __restrict__ gcursor,
                                                  int2* __restrict__ pair, int nb) {
    __shared__ int h[BSZ];
    __shared__ int cur[BSZ];
    int t = threadIdx.x;
    h[t] = 0;
    __syncthreads();
    int stride = gridDim.x * blockDim.x;
    for (int e = blockIdx.x * blockDim.x + t; e < E; e += stride)
        atomicAdd(&h[col[e] >> BSH], 1);
    __syncthreads();
    {
        int c = h[t];
        cur[t] = (t < nb && c > 0) ? atomicAdd(&gcursor[t], c) : 0;
    }
    __syncthreads();
    for (int e = blockIdx.x * blockDim.x + t; e < E; e += stride) {
        int c = col[e];
        int pos = atomicAdd(&cur[c >> BSH], 1);
        pair[pos] = make_int2(row[e], c);
    }
}

// ---------------- CSR pass D: per-bucket fine CSR build (one block per bucket) ----
// All per-edge atomics are LDS; csr writes confined to this bucket's ~16KB
// window on one XCD's L2 -> fully merged writebacks.
__global__ __launch_bounds__(256) void k_bcsr(const int2* __restrict__ pair,
                                              const int* __restrict__ base,
                                              int* __restrict__ rowptr,
                                              int* __restrict__ cnt,
                                              float* __restrict__ dinv,
                                              int* __restrict__ csr, int n) {
    __shared__ int lcnt[BSZ];
    __shared__ int ssc[BSZ];
    __shared__ int lcur[BSZ];
    const int b = blockIdx.x;
    const int t = threadIdx.x;
    const int nd0 = b << BSH;
    const int e0 = base[b];
    const int e1 = base[b + 1];

    lcnt[t] = 0;
    __syncthreads();
    for (int e = e0 + t; e < e1; e += 256)
        atomicAdd(&lcnt[pair[e].y & (BSZ - 1)], 1);
    __syncthreads();
    int v = lcnt[t];
    ssc[t] = v;
    __syncthreads();
    for (int d = 1; d < 256; d <<= 1) {
        int x = ssc[t];
        if (t >= d) x += ssc[t - d];
        __syncthreads();
        ssc[t] = x;
        __syncthreads();
    }
    int excl = ssc[t] - v;
    lcur[t] = e0 + excl;
    int node = nd0 + t;
    if (node < n) {
        rowptr[node] = e0 + excl;
        cnt[node]    = v;
        dinv[node]   = rsqrtf((float)(v + 1));
    }
    __syncthreads();
    for (int e = e0 + t; e < e1; e += 256) {
        int2 p = pair[e];
        int pos = atomicAdd(&lcur[p.y & (BSZ - 1)], 1);
        csr[pos] = p.x;
    }
}

// ---------------- dense transform: 64-node tile, optional dinv pre-scale ----------------
// FIN=128 LDS = 128*64*4 + 32*68*4 = 41472 B -> 3 blocks/CU max; FIN=64 -> 4.
template<int FIN, bool SCALE>
__global__ __launch_bounds__(256, (FIN == 128) ? 3 : 4)
void k_gemm(const float* __restrict__ x, const float* __restrict__ W,
            const float* __restrict__ dinv, float* __restrict__ out, int n) {
    constexpr int KC = 32;
    constexpr int XS = 68;
    __shared__ __align__(16) float Ws[FIN][HH];
    __shared__ __align__(16) float xs_t[KC][XS];
    const int tid = threadIdx.x;
    const int tx = tid & 15;
    const int ty = tid >> 4;
    const int node0 = blockIdx.x * 64;
    if (node0 >= n) return;

    for (int i = tid * 4; i < FIN * HH; i += 1024)
        *(float4*)&Ws[0][i] = *(const float4*)&W[i];

    float acc[4][4] = {};
    const int rr0 = tid >> 3;
    const int cc  = (tid & 7) * 4;

    for (int kc = 0; kc < FIN; kc += KC) {
        __syncthreads();
        for (int rr = rr0; rr < 64; rr += 32) {
            float4 v = make_float4(0.f, 0.f, 0.f, 0.f);
            if (node0 + rr < n) v = *(const float4*)&x[(size_t)(node0 + rr) * FIN + kc + cc];
            xs_t[cc + 0][rr] = v.x;
            xs_t[cc + 1][rr] = v.y;
            xs_t[cc + 2][rr] = v.z;
            xs_t[cc + 3][rr] = v.w;
        }
        __syncthreads();
#pragma unroll 4
        for (int k = 0; k < KC; ++k) {
            float4 a4 = *(const float4*)&xs_t[k][ty * 4];
            float4 b4 = *(const float4*)&Ws[kc + k][tx * 4];
            acc[0][0] = fmaf(a4.x, b4.x, acc[0][0]);
            acc[0][1] = fmaf(a4.x, b4.y, acc[0][1]);
            acc[0][2] = fmaf(a4.x, b4.z, acc[0][2]);
            acc[0][3] = fmaf(a4.x, b4.w, acc[0][3]);
            acc[1][0] = fmaf(a4.y, b4.x, acc[1][0]);
            acc[1][1] = fmaf(a4.y, b4.y, acc[1][1]);
            acc[1][2] = fmaf(a4.y, b4.z, acc[1][2]);
            acc[1][3] = fmaf(a4.y, b4.w, acc[1][3]);
            acc[2][0] = fmaf(a4.z, b4.x, acc[2][0]);
            acc[2][1] = fmaf(a4.z, b4.y, acc[2][1]);
            acc[2][2] = fmaf(a4.z, b4.z, acc[2][2]);
            acc[2][3] = fmaf(a4.z, b4.w, acc[2][3]);
            acc[3][0] = fmaf(a4.w, b4.x, acc[3][0]);
            acc[3][1] = fmaf(a4.w, b4.y, acc[3][1]);
            acc[3][2] = fmaf(a4.w, b4.z, acc[3][2]);
            acc[3][3] = fmaf(a4.w, b4.w, acc[3][3]);
        }
    }

#pragma unroll
    for (int i = 0; i < 4; ++i) {
        int node = node0 + ty * 4 + i;
        if (node < n) {
            if (SCALE) {
                float d = dinv[node];
                float4 o = make_float4(acc[i][0] * d, acc[i][1] * d,
                                       acc[i][2] * d, acc[i][3] * d);
                *(float4*)&out[(size_t)node * HH + tx * 4] = o;
            } else {
                *(float4*)&out[(size_t)node * HH + tx * 4] = *(float4*)acc[i];
            }
        }
    }
}

// ---------------- gather: quarter-wave float4 (R17-verified structure) ----------------
// WEIGHTED (layer 1): lin unscaled, per-edge weight dinv[src], self weight di.
// else (layers 2-3): linS pre-scaled, weight 1, self weight 1.
// All cross-lane shfls UNCONDITIONAL (uniform exec — the R14 lesson); range
// guards live in wv only. Source lane j+q*4+t <= 63, no wrap needed.
template<bool WEIGHTED>
__global__ __launch_bounds__(256) void k_gather_q(const float* __restrict__ lin,
                                                  const int* __restrict__ csr,
                                                  const int* __restrict__ rowptr,
                                                  const int* __restrict__ cnt,
                                                  const float* __restrict__ dinv,
                                                  const float* __restrict__ b,
                                                  float* __restrict__ hout, int n) {
    int node = blockIdx.x * 4 + (threadIdx.x >> 6);
    int lane = threadIdx.x & 63;
    if (node >= n) return;
    const int q  = lane >> 4;          // quarter 0..3
    const int fl = (lane & 15) * 4;    // float4 feature offset
    int start = rowptr[node];
    int end = start + cnt[node];
    float di = dinv[node];

    float4 a0 = make_float4(0.f, 0.f, 0.f, 0.f);
    float4 a1 = make_float4(0.f, 0.f, 0.f, 0.f);

    for (int base = start; base < end; base += 64) {
        int m = end - base; if (m > 64) m = 64;
        int idx = base + lane;
        int   sv = (idx < end) ? csr[idx] : 0;
        float wv;
        if (WEIGHTED) wv = (idx < end) ? dinv[sv] : 0.f;   // predicated load: safe
        else          wv = (idx < end) ? 1.f : 0.f;
        for (int j = 0; j < m; j += 16) {
            int l = j + q * 4;                       // <= 63 always
            int   s0 = __shfl(sv, l, 64);            // unconditional, uniform
            int   s1 = __shfl(sv, l + 1, 64);
            int   s2 = __shfl(sv, l + 2, 64);
            int   s3 = __shfl(sv, l + 3, 64);
            float w0 = __shfl(wv, l, 64);
            float w1 = __shfl(wv, l + 1, 64);
            float w2 = __shfl(wv, l + 2, 64);
            float w3 = __shfl(wv, l + 3, 64);
            float4 v0 = *(const float4*)&lin[(size_t)s0 * HH + fl];
            float4 v1 = *(const float4*)&lin[(size_t)s1 * HH + fl];
            float4 v2 = *(const float4*)&lin[(size_t)s2 * HH + fl];
            float4 v3 = *(const float4*)&lin[(size_t)s3 * HH + fl];
            a0.x = fmaf(w0, v0.x, a0.x); a0.y = fmaf(w0, v0.y, a0.y);
            a0.z = fmaf(w0, v0.z, a0.z); a0.w = fmaf(w0, v0.w, a0.w);
            a1.x = fmaf(w1, v1.x, a1.x); a1.y = fmaf(w1, v1.y, a1.y);
            a1.z = fmaf(w1, v1.z, a1.z); a1.w = fmaf(w1, v1.w, a1.w);
            a0.x = fmaf(w2, v2.x, a0.x); a0.y = fmaf(w2, v2.y, a0.y);
            a0.z = fmaf(w2, v2.z, a0.z); a0.w = fmaf(w2, v2.w, a0.w);
            a1.x = fmaf(w3, v3.x, a1.x); a1.y = fmaf(w3, v3.y, a1.y);
            a1.z = fmaf(w3, v3.z, a1.z); a1.w = fmaf(w3, v3.w, a1.w);
        }
    }
    float4 acc = make_float4(a0.x + a1.x, a0.y + a1.y, a0.z + a1.z, a0.w + a1.w);
#pragma unroll
    for (int off = 16; off < 64; off <<= 1) {
        acc.x += __shfl_xor(acc.x, off, 64);
        acc.y += __shfl_xor(acc.y, off, 64);
        acc.z += __shfl_xor(acc.z, off, 64);
        acc.w += __shfl_xor(acc.w, off, 64);
    }
    // self-loop term: weight di (weighted) or 1 (pre-scaled input)
    float4 self = *(const float4*)&lin[(size_t)node * HH + fl];
    float sw = WEIGHTED ? di : 1.f;
    acc.x = fmaf(sw, self.x, acc.x);
    acc.y = fmaf(sw, self.y, acc.y);
    acc.z = fmaf(sw, self.z, acc.z);
    acc.w = fmaf(sw, self.w, acc.w);
    // bias + L2 norm + relu
    float4 b4 = *(const float4*)&b[fl];
    float4 v4 = make_float4(fmaf(di, acc.x, b4.x), fmaf(di, acc.y, b4.y),
                            fmaf(di, acc.z, b4.z), fmaf(di, acc.w, b4.w));
    float ss = v4.x * v4.x + v4.y * v4.y + v4.z * v4.z + v4.w * v4.w;
#pragma unroll
    for (int off = 1; off < 16; off <<= 1) ss += __shfl_xor(ss, off, 64);
    float inv = 1.f / fmaxf(sqrtf(ss), 1e-12f);
    v4.x = fmaxf(v4.x * inv, 0.f);
    v4.y = fmaxf(v4.y * inv, 0.f);
    v4.z = fmaxf(v4.z * inv, 0.f);
    v4.w = fmaxf(v4.w * inv, 0.f);
    if (q == 0) *(float4*)&hout[(size_t)node * HH + fl] = v4;
}

// ---------------- pooling ----------------
__global__ __launch_bounds__(256) void k_pool(const float* __restrict__ node_emb,
                                              const int* __restrict__ batch,
                                              float* __restrict__ sums,
                                              float* __restrict__ cnts, int n) {
    const int NPW = 16;
    int wave = blockIdx.x * 4 + (threadIdx.x >> 6);
    int lane = threadIdx.x & 63;
    int start = wave * NPW;
    if (start >= n) return;
    int end = start + NPW; if (end > n) end = n;
    int cur = batch[start];
    float acc = 0.f;
    int runlen = 0;
    for (int node = start; node < end; ++node) {
        int g = batch[node];
        if (g != cur) {
            atomicAdd(&sums[(size_t)cur * HH + lane], acc);
            if (lane == 0) atomicAdd(&cnts[cur], (float)runlen);
            acc = 0.f; runlen = 0; cur = g;
        }
        acc += node_emb[(size_t)node * HH + lane];
        ++runlen;
    }
    atomicAdd(&sums[(size_t)cur * HH + lane], acc);
    if (lane == 0) atomicAdd(&cnts[cur], (float)runlen);
}

// ---------------- classifier + softmax ----------------
__global__ void k_final2(const float* __restrict__ sums, const float* __restrict__ cnts,
                         const float* __restrict__ Wm, const float* __restrict__ bm,
                         float* __restrict__ logits, float* __restrict__ probs,
                         float* __restrict__ graph_emb) {
    int g = blockIdx.x;
    int lane = threadIdx.x;
    float mean = sums[(size_t)g * HH + lane] / fmaxf(cnts[g], 1.0f);
    graph_emb[(size_t)g * HH + lane] = mean;

    __shared__ float semb[HH];
    __shared__ float slog[16];
    semb[lane] = mean;
    __syncthreads();
    if (lane < 10) {
        float acc = bm[lane];
        for (int k = 0; k < HH; ++k) acc = fmaf(semb[k], Wm[k * 10 + lane], acc);
        slog[lane] = acc;
    }
    __syncthreads();
    if (lane < 10) {
        float mx = -1e30f;
        for (int j = 0; j < 10; ++j) mx = fmaxf(mx, slog[j]);
        float den = 0.f;
        for (int j = 0; j < 10; ++j) den += __expf(slog[j] - mx);
        float lg = slog[lane];
        logits[g * 10 + lane] = lg;
        probs[g * 10 + lane] = __expf(lg - mx) / den;
    }
}

// ---------------- launch ----------------

extern "C" void kernel_launch(void* const* d_in, const int* in_sizes, int n_in,
                              void* d_out, int out_size, void* d_ws, size_t ws_size,
                              hipStream_t stream) {
    const float* x     = (const float*)d_in[0];
    const int*   ei    = (const int*)  d_in[1];
    const int*   batch = (const int*)  d_in[2];
    const float* W1 = (const float*)d_in[3];  const float* b1 = (const float*)d_in[4];
    const float* W2 = (const float*)d_in[5];  const float* b2 = (const float*)d_in[6];
    const float* W3 = (const float*)d_in[7];  const float* b3 = (const float*)d_in[8];
    const float* Wm = (const float*)d_in[9];  const float* bm = (const float*)d_in[10];

    const int N = in_sizes[2];
    const int E = in_sizes[1] / 2;
    const int G = (out_size - N * HH) / (2 * 10 + HH);
    const int NB = (N + BSZ - 1) >> BSH;     // buckets (196 for N=50000)

    const int* row = ei;
    const int* col = ei + E;

    float* out       = (float*)d_out;
    float* logits    = out;
    float* probs     = out + (size_t)G * 10;
    float* node_emb  = out + (size_t)2 * G * 10;
    float* graph_emb = node_emb + (size_t)N * HH;

    char* w = (char*)d_ws;
    auto alloc = [&](size_t bytes) { char* p = w; w += (bytes + 255) & ~(size_t)255; return p; };
    float* dinv    = (float*)alloc((size_t)N * 4);
    int*   cnt     = (int*)  alloc((size_t)N * 4);
    int*   rowptr  = (int*)  alloc((size_t)N * 4);
    int*   bucket_cnt    = (int*)alloc((size_t)(NB + 1) * 4);
    int*   bucket_base   = (int*)alloc((size_t)(NB + 1) * 4);
    int*   bucket_cursor = (int*)alloc((size_t)(NB + 1) * 4);
    float* sums    = (float*)alloc((size_t)G * HH * 4 + (size_t)G * 4);
    float* cnts    = sums + (size_t)G * HH;
    int2*  pairbuf = (int2*) alloc((size_t)E * 8);
    int*   csr     = (int*)  alloc((size_t)E * 4);
    float* bufA    = (float*)alloc((size_t)N * HH * 4);
    float* bufB    = (float*)alloc((size_t)N * HH * 4);

    const int B = 256;
    dim3 blk(B);
    int node_blocks = (N + 3) / 4;
    int gemm_blocks = (N + 63) / 64;
    int poolN = G * HH + G;
    int initB = (poolN + B - 1) / B;
    int pool_blocks = (N + 63) / 64;

    // CSR build: LDS-binned hierarchical bucketing — no per-edge global atomics.
    k_init<<<initB, blk, 0, stream>>>(bucket_cnt, sums, NB, poolN);
    k_bhist<<<256, blk, 0, stream>>>(col, E, bucket_cnt, NB);
    k_bscan<<<1, blk, 0, stream>>>(bucket_cnt, bucket_base, bucket_cursor, NB);
    k_bscatter<<<256, blk, 0, stream>>>(row, col, E, bucket_cursor, pairbuf, NB);
    k_bcsr<<<NB, blk, 0, stream>>>(pairbuf, bucket_base, rowptr, cnt, dinv, csr, N);

    // layer 1: dense transform (unscaled) + weighted quarter-wave gather
    k_gemm<128, false><<<gemm_blocks, blk, 0, stream>>>(x, W1, dinv, bufA, N);
    k_gather_q<true><<<node_blocks, blk, 0, stream>>>(bufA, csr, rowptr, cnt, dinv, b1, bufB, N);
    // layer 2: prescaled gemm + quarter-wave gather (bufB -> bufA -> bufB = h2)
    k_gemm<64, true><<<gemm_blocks, blk, 0, stream>>>(bufB, W2, dinv, bufA, N);
    k_gather_q<false><<<node_blocks, blk, 0, stream>>>(bufA, csr, rowptr, cnt, dinv, b2, bufB, N);
    // layer 3: prescaled gemm + quarter-wave gather (bufB -> bufA -> node_emb)
    k_gemm<64, true><<<gemm_blocks, blk, 0, stream>>>(bufB, W3, dinv, bufA, N);
    k_gather_q<false><<<node_blocks, blk, 0, stream>>>(bufA, csr, rowptr, cnt, dinv, b3, node_emb, N);

    // pool + classifier
    k_pool<<<pool_blocks, blk, 0, stream>>>(node_emb, batch, sums, cnts, N);
    k_final2<<<G, dim3(64), 0, stream>>>(sums, cnts, Wm, bm, logits, probs, graph_emb);
}

// Round 4
// 265.061 us; speedup vs baseline: 1.3336x; 1.0711x over previous
//
#include <hip/hip_runtime.h>
#include <math.h>

#define HH 64
// Bucket = col >> 8 (256 nodes per bucket). Assumes N <= 65536 (N=50000 here)
// — also required by the 16-bit row packing in pairbuf.
#define BSH 8
#define BSZ 256

typedef _Float16 half_t;
typedef _Float16 half4_t __attribute__((ext_vector_type(4)));

// ---------------- init ----------------

__global__ void k_init(int* __restrict__ bucket_cnt, float* __restrict__ sums,
                       int nb, int pn) {
    int i = blockIdx.x * blockDim.x + threadIdx.x;
    if (i < nb) bucket_cnt[i] = 0;
    if (i < pn) sums[i] = 0.f;
}

// ---------------- CSR pass A: bucket histogram via LDS (no per-edge global atomics) ----
__global__ __launch_bounds__(256) void k_bhist(const int* __restrict__ col, int E,
                                               int* __restrict__ bucket_cnt, int nb) {
    __shared__ int h[BSZ];
    int t = threadIdx.x;
    h[t] = 0;
    __syncthreads();
    int stride = gridDim.x * blockDim.x;
    for (int e = blockIdx.x * blockDim.x + t; e < E; e += stride)
        atomicAdd(&h[col[e] >> BSH], 1);
    __syncthreads();
    if (t < nb && h[t]) atomicAdd(&bucket_cnt[t], h[t]);
}

// ---------------- CSR pass B: exclusive scan of bucket counts (single block) ----
__global__ __launch_bounds__(256) void k_bscan(const int* __restrict__ bc,
                                               int* __restrict__ base,
                                               int* __restrict__ cursor, int nb) {
    __shared__ int s[256];
    __shared__ int carry_s;
    int t = threadIdx.x;
    if (t == 0) carry_s = 0;
    __syncthreads();
    for (int off = 0; off < nb; off += 256) {
        int i = off + t;
        int v = (i < nb) ? bc[i] : 0;
        s[t] = v;
        __syncthreads();
        for (int d = 1; d < 256; d <<= 1) {
            int x = s[t];
            if (t >= d) x += s[t - d];
            __syncthreads();
            s[t] = x;
            __syncthreads();
        }
        int carry = carry_s;
        int excl = carry + s[t] - v;
        if (i < nb) { base[i] = excl; cursor[i] = excl; }
        int tot = s[255];
        __syncthreads();
        if (t == 0) carry_s = carry + tot;
        __syncthreads();
    }
    if (t == 0) base[nb] = carry_s;
}

// ---------------- CSR pass C: scatter edges into bucket-contiguous packed list ----
// One global atomic per (block,bucket) reservation (~50k total). Packed entry:
// bits 0-15 = row (N < 65536), bits 16-23 = col & 255. Halves pair traffic.
__global__ __launch_bounds__(256) void k_bscatter(const int* __restrict__ row,
                                                  const int* __restrict__ col, int E,
                                                  int* __restrict__ gcursor,
                                                  int* __restrict__ pair, int nb) {
    __shared__ int h[BSZ];
    __shared__ int cur[BSZ];
    int t = threadIdx.x;
    h[t] = 0;
    __syncthreads();
    int stride = gridDim.x * blockDim.x;
    for (int e = blockIdx.x * blockDim.x + t; e < E; e += stride)
        atomicAdd(&h[col[e] >> BSH], 1);
    __syncthreads();
    {
        int c = h[t];
        cur[t] = (t < nb && c > 0) ? atomicAdd(&gcursor[t], c) : 0;
    }
    __syncthreads();
    for (int e = blockIdx.x * blockDim.x + t; e < E; e += stride) {
        int c = col[e];
        int pos = atomicAdd(&cur[c >> BSH], 1);
        pair[pos] = (row[e] & 0xFFFF) | ((c & (BSZ - 1)) << 16);
    }
}

// ---------------- CSR pass D: per-bucket fine CSR build (one block per bucket) ----
// All per-edge atomics are LDS; csr writes confined to the bucket's window.
__global__ __launch_bounds__(256) void k_bcsr(const int* __restrict__ pair,
                                              const int* __restrict__ base,
                                              int* __restrict__ rowptr,
                                              int* __restrict__ cnt,
                                              float* __restrict__ dinv,
                                              int* __restrict__ csr, int n) {
    __shared__ int lcnt[BSZ];
    __shared__ int ssc[BSZ];
    __shared__ int lcur[BSZ];
    const int b = blockIdx.x;
    const int t = threadIdx.x;
    const int nd0 = b << BSH;
    const int e0 = base[b];
    const int e1 = base[b + 1];

    lcnt[t] = 0;
    __syncthreads();
    for (int e = e0 + t; e < e1; e += 256)
        atomicAdd(&lcnt[(pair[e] >> 16) & (BSZ - 1)], 1);
    __syncthreads();
    int v = lcnt[t];
    ssc[t] = v;
    __syncthreads();
    for (int d = 1; d < 256; d <<= 1) {
        int x = ssc[t];
        if (t >= d) x += ssc[t - d];
        __syncthreads();
        ssc[t] = x;
        __syncthreads();
    }
    int excl = ssc[t] - v;
    lcur[t] = e0 + excl;
    int node = nd0 + t;
    if (node < n) {
        rowptr[node] = e0 + excl;
        cnt[node]    = v;
        dinv[node]   = rsqrtf((float)(v + 1));
    }
    __syncthreads();
    for (int e = e0 + t; e < e1; e += 256) {
        int p = pair[e];
        int pos = atomicAdd(&lcur[(p >> 16) & (BSZ - 1)], 1);
        csr[pos] = p & 0xFFFF;
    }
}

// ---------------- dense transform: 64-node tile, fp16-in/out options ----------------
// Accumulation fp32 in registers; LDS tiles fp32. HIN: input is half. HOUT: out half.
template<int FIN, bool SCALE, bool HIN, bool HOUT>
__global__ __launch_bounds__(256, (FIN == 128) ? 3 : 4)
void k_gemm(const void* __restrict__ xin, const float* __restrict__ W,
            const float* __restrict__ dinv, void* __restrict__ out, int n) {
    constexpr int KC = 32;
    constexpr int XS = 68;
    __shared__ __align__(16) float Ws[FIN][HH];
    __shared__ __align__(16) float xs_t[KC][XS];
    const int tid = threadIdx.x;
    const int tx = tid & 15;
    const int ty = tid >> 4;
    const int node0 = blockIdx.x * 64;
    if (node0 >= n) return;

    for (int i = tid * 4; i < FIN * HH; i += 1024)
        *(float4*)&Ws[0][i] = *(const float4*)&W[i];

    float acc[4][4] = {};
    const int rr0 = tid >> 3;
    const int cc  = (tid & 7) * 4;

    for (int kc = 0; kc < FIN; kc += KC) {
        __syncthreads();
        for (int rr = rr0; rr < 64; rr += 32) {
            float4 v = make_float4(0.f, 0.f, 0.f, 0.f);
            if (node0 + rr < n) {
                if constexpr (HIN) {
                    half4_t hv = *(const half4_t*)((const half_t*)xin +
                                   (size_t)(node0 + rr) * FIN + kc + cc);
                    v = make_float4((float)hv.x, (float)hv.y, (float)hv.z, (float)hv.w);
                } else {
                    v = *(const float4*)((const float*)xin +
                                   (size_t)(node0 + rr) * FIN + kc + cc);
                }
            }
            xs_t[cc + 0][rr] = v.x;
            xs_t[cc + 1][rr] = v.y;
            xs_t[cc + 2][rr] = v.z;
            xs_t[cc + 3][rr] = v.w;
        }
        __syncthreads();
#pragma unroll 4
        for (int k = 0; k < KC; ++k) {
            float4 a4 = *(const float4*)&xs_t[k][ty * 4];
            float4 b4 = *(const float4*)&Ws[kc + k][tx * 4];
            acc[0][0] = fmaf(a4.x, b4.x, acc[0][0]);
            acc[0][1] = fmaf(a4.x, b4.y, acc[0][1]);
            acc[0][2] = fmaf(a4.x, b4.z, acc[0][2]);
            acc[0][3] = fmaf(a4.x, b4.w, acc[0][3]);
            acc[1][0] = fmaf(a4.y, b4.x, acc[1][0]);
            acc[1][1] = fmaf(a4.y, b4.y, acc[1][1]);
            acc[1][2] = fmaf(a4.y, b4.z, acc[1][2]);
            acc[1][3] = fmaf(a4.y, b4.w, acc[1][3]);
            acc[2][0] = fmaf(a4.z, b4.x, acc[2][0]);
            acc[2][1] = fmaf(a4.z, b4.y, acc[2][1]);
            acc[2][2] = fmaf(a4.z, b4.z, acc[2][2]);
            acc[2][3] = fmaf(a4.z, b4.w, acc[2][3]);
            acc[3][0] = fmaf(a4.w, b4.x, acc[3][0]);
            acc[3][1] = fmaf(a4.w, b4.y, acc[3][1]);
            acc[3][2] = fmaf(a4.w, b4.z, acc[3][2]);
            acc[3][3] = fmaf(a4.w, b4.w, acc[3][3]);
        }
    }

#pragma unroll
    for (int i = 0; i < 4; ++i) {
        int node = node0 + ty * 4 + i;
        if (node < n) {
            float d = SCALE ? dinv[node] : 1.f;
            float r0 = acc[i][0] * d, r1 = acc[i][1] * d;
            float r2 = acc[i][2] * d, r3 = acc[i][3] * d;
            if constexpr (HOUT) {
                half4_t o = {(half_t)r0, (half_t)r1, (half_t)r2, (half_t)r3};
                *(half4_t*)((half_t*)out + (size_t)node * HH + tx * 4) = o;
            } else {
                *(float4*)((float*)out + (size_t)node * HH + tx * 4) =
                    make_float4(r0, r1, r2, r3);
            }
        }
    }
}

// ---------------- gather: quarter-wave, fp16 rows (128 B/row), fp32 accumulate ----
// WEIGHTED (layer 1): lin unscaled, per-edge weight dinv[src], self weight di.
// else (layers 2-3): linS pre-scaled, weight 1, self weight 1.
// HOUT: write half (feeds next gemm) or float (node_emb output).
// All cross-lane shfls UNCONDITIONAL (uniform exec); range guards in wv only.
template<bool WEIGHTED, bool HOUT>
__global__ __launch_bounds__(256) void k_gather_q(const half_t* __restrict__ lin,
                                                  const int* __restrict__ csr,
                                                  const int* __restrict__ rowptr,
                                                  const int* __restrict__ cnt,
                                                  const float* __restrict__ dinv,
                                                  const float* __restrict__ b,
                                                  void* __restrict__ hout, int n) {
    int node = blockIdx.x * 4 + (threadIdx.x >> 6);
    int lane = threadIdx.x & 63;
    if (node >= n) return;
    const int q  = lane >> 4;          // quarter 0..3
    const int fl = (lane & 15) * 4;    // feature offset (in elements)
    int start = rowptr[node];
    int end = start + cnt[node];
    float di = dinv[node];

    float4 a0 = make_float4(0.f, 0.f, 0.f, 0.f);
    float4 a1 = make_float4(0.f, 0.f, 0.f, 0.f);

    for (int base = start; base < end; base += 64) {
        int m = end - base; if (m > 64) m = 64;
        int idx = base + lane;
        int   sv = (idx < end) ? csr[idx] : 0;
        float wv;
        if (WEIGHTED) wv = (idx < end) ? dinv[sv] : 0.f;   // predicated load: safe
        else          wv = (idx < end) ? 1.f : 0.f;
        for (int j = 0; j < m; j += 16) {
            int l = j + q * 4;                       // <= 63 always
            int   s0 = __shfl(sv, l, 64);            // unconditional, uniform
            int   s1 = __shfl(sv, l + 1, 64);
            int   s2 = __shfl(sv, l + 2, 64);
            int   s3 = __shfl(sv, l + 3, 64);
            float w0 = __shfl(wv, l, 64);
            float w1 = __shfl(wv, l + 1, 64);
            float w2 = __shfl(wv, l + 2, 64);
            float w3 = __shfl(wv, l + 3, 64);
            half4_t v0 = *(const half4_t*)&lin[(size_t)s0 * HH + fl];
            half4_t v1 = *(const half4_t*)&lin[(size_t)s1 * HH + fl];
            half4_t v2 = *(const half4_t*)&lin[(size_t)s2 * HH + fl];
            half4_t v3 = *(const half4_t*)&lin[(size_t)s3 * HH + fl];
            a0.x = fmaf(w0, (float)v0.x, a0.x); a0.y = fmaf(w0, (float)v0.y, a0.y);
            a0.z = fmaf(w0, (float)v0.z, a0.z); a0.w = fmaf(w0, (float)v0.w, a0.w);
            a1.x = fmaf(w1, (float)v1.x, a1.x); a1.y = fmaf(w1, (float)v1.y, a1.y);
            a1.z = fmaf(w1, (float)v1.z, a1.z); a1.w = fmaf(w1, (float)v1.w, a1.w);
            a0.x = fmaf(w2, (float)v2.x, a0.x); a0.y = fmaf(w2, (float)v2.y, a0.y);
            a0.z = fmaf(w2, (float)v2.z, a0.z); a0.w = fmaf(w2, (float)v2.w, a0.w);
            a1.x = fmaf(w3, (float)v3.x, a1.x); a1.y = fmaf(w3, (float)v3.y, a1.y);
            a1.z = fmaf(w3, (float)v3.z, a1.z); a1.w = fmaf(w3, (float)v3.w, a1.w);
        }
    }
    float4 acc = make_float4(a0.x + a1.x, a0.y + a1.y, a0.z + a1.z, a0.w + a1.w);
#pragma unroll
    for (int off = 16; off < 64; off <<= 1) {
        acc.x += __shfl_xor(acc.x, off, 64);
        acc.y += __shfl_xor(acc.y, off, 64);
        acc.z += __shfl_xor(acc.z, off, 64);
        acc.w += __shfl_xor(acc.w, off, 64);
    }
    // self-loop term: weight di (weighted) or 1 (pre-scaled input)
    half4_t self = *(const half4_t*)&lin[(size_t)node * HH + fl];
    float sw = WEIGHTED ? di : 1.f;
    acc.x = fmaf(sw, (float)self.x, acc.x);
    acc.y = fmaf(sw, (float)self.y, acc.y);
    acc.z = fmaf(sw, (float)self.z, acc.z);
    acc.w = fmaf(sw, (float)self.w, acc.w);
    // bias + L2 norm + relu
    float4 b4 = *(const float4*)&b[fl];
    float4 v4 = make_float4(fmaf(di, acc.x, b4.x), fmaf(di, acc.y, b4.y),
                            fmaf(di, acc.z, b4.z), fmaf(di, acc.w, b4.w));
    float ss = v4.x * v4.x + v4.y * v4.y + v4.z * v4.z + v4.w * v4.w;
#pragma unroll
    for (int off = 1; off < 16; off <<= 1) ss += __shfl_xor(ss, off, 64);
    float inv = 1.f / fmaxf(sqrtf(ss), 1e-12f);
    v4.x = fmaxf(v4.x * inv, 0.f);
    v4.y = fmaxf(v4.y * inv, 0.f);
    v4.z = fmaxf(v4.z * inv, 0.f);
    v4.w = fmaxf(v4.w * inv, 0.f);
    if (q == 0) {
        if constexpr (HOUT) {
            half4_t o = {(half_t)v4.x, (half_t)v4.y, (half_t)v4.z, (half_t)v4.w};
            *(half4_t*)((half_t*)hout + (size_t)node * HH + fl) = o;
        } else {
            *(float4*)((float*)hout + (size_t)node * HH + fl) = v4;
        }
    }
}

// ---------------- pooling ----------------
__global__ __launch_bounds__(256) void k_pool(const float* __restrict__ node_emb,
                                              const int* __restrict__ batch,
                                              float* __restrict__ sums,
                                              float* __restrict__ cnts, int n) {
    const int NPW = 16;
    int wave = blockIdx.x * 4 + (threadIdx.x >> 6);
    int lane = threadIdx.x & 63;
    int start = wave * NPW;
    if (start >= n) return;
    int end = start + NPW; if (end > n) end = n;
    int cur = batch[start];
    float acc = 0.f;
    int runlen = 0;
    for (int node = start; node < end; ++node) {
        int g = batch[node];
        if (g != cur) {
            atomicAdd(&sums[(size_t)cur * HH + lane], acc);
            if (lane == 0) atomicAdd(&cnts[cur], (float)runlen);
            acc = 0.f; runlen = 0; cur = g;
        }
        acc += node_emb[(size_t)node * HH + lane];
        ++runlen;
    }
    atomicAdd(&sums[(size_t)cur * HH + lane], acc);
    if (lane == 0) atomicAdd(&cnts[cur], (float)runlen);
}

// ---------------- classifier + softmax ----------------
__global__ void k_final2(const float* __restrict__ sums, const float* __restrict__ cnts,
                         const float* __restrict__ Wm, const float* __restrict__ bm,
                         float* __restrict__ logits, float* __restrict__ probs,
                         float* __restrict__ graph_emb) {
    int g = blockIdx.x;
    int lane = threadIdx.x;
    float mean = sums[(size_t)g * HH + lane] / fmaxf(cnts[g], 1.0f);
    graph_emb[(size_t)g * HH + lane] = mean;

    __shared__ float semb[HH];
    __shared__ float slog[16];
    semb[lane] = mean;
    __syncthreads();
    if (lane < 10) {
        float acc = bm[lane];
        for (int k = 0; k < HH; ++k) acc = fmaf(semb[k], Wm[k * 10 + lane], acc);
        slog[lane] = acc;
    }
    __syncthreads();
    if (lane < 10) {
        float mx = -1e30f;
        for (int j = 0; j < 10; ++j) mx = fmaxf(mx, slog[j]);
        float den = 0.f;
        for (int j = 0; j < 10; ++j) den += __expf(slog[j] - mx);
        float lg = slog[lane];
        logits[g * 10 + lane] = lg;
        probs[g * 10 + lane] = __expf(lg - mx) / den;
    }
}

// ---------------- launch ----------------

extern "C" void kernel_launch(void* const* d_in, const int* in_sizes, int n_in,
                              void* d_out, int out_size, void* d_ws, size_t ws_size,
                              hipStream_t stream) {
    const float* x     = (const float*)d_in[0];
    const int*   ei    = (const int*)  d_in[1];
    const int*   batch = (const int*)  d_in[2];
    const float* W1 = (const float*)d_in[3];  const float* b1 = (const float*)d_in[4];
    const float* W2 = (const float*)d_in[5];  const float* b2 = (const float*)d_in[6];
    const float* W3 = (const float*)d_in[7];  const float* b3 = (const float*)d_in[8];
    const float* Wm = (const float*)d_in[9];  const float* bm = (const float*)d_in[10];

    const int N = in_sizes[2];
    const int E = in_sizes[1] / 2;
    const int G = (out_size - N * HH) / (2 * 10 + HH);
    const int NB = (N + BSZ - 1) >> BSH;     // buckets (196 for N=50000)

    const int* row = ei;
    const int* col = ei + E;

    float* out       = (float*)d_out;
    float* logits    = out;
    float* probs     = out + (size_t)G * 10;
    float* node_emb  = out + (size_t)2 * G * 10;
    float* graph_emb = node_emb + (size_t)N * HH;

    char* w = (char*)d_ws;
    auto alloc = [&](size_t bytes) { char* p = w; w += (bytes + 255) & ~(size_t)255; return p; };
    float* dinv    = (float*)alloc((size_t)N * 4);
    int*   cnt     = (int*)  alloc((size_t)N * 4);
    int*   rowptr  = (int*)  alloc((size_t)N * 4);
    int*   bucket_cnt    = (int*)alloc((size_t)(NB + 1) * 4);
    int*   bucket_base   = (int*)alloc((size_t)(NB + 1) * 4);
    int*   bucket_cursor = (int*)alloc((size_t)(NB + 1) * 4);
    float* sums    = (float*)alloc((size_t)G * HH * 4 + (size_t)G * 4);
    float* cnts    = sums + (size_t)G * HH;
    int*   pairbuf = (int*)  alloc((size_t)E * 4);
    int*   csr     = (int*)  alloc((size_t)E * 4);
    half_t* bufA   = (half_t*)alloc((size_t)N * HH * 2);
    half_t* bufB   = (half_t*)alloc((size_t)N * HH * 2);

    const int B = 256;
    dim3 blk(B);
    int node_blocks = (N + 3) / 4;
    int gemm_blocks = (N + 63) / 64;
    int poolN = G * HH + G;
    int initB = (poolN + B - 1) / B;
    int pool_blocks = (N + 63) / 64;

    // CSR build: LDS-binned hierarchical bucketing — no per-edge global atomics.
    k_init<<<initB, blk, 0, stream>>>(bucket_cnt, sums, NB, poolN);
    k_bhist<<<256, blk, 0, stream>>>(col, E, bucket_cnt, NB);
    k_bscan<<<1, blk, 0, stream>>>(bucket_cnt, bucket_base, bucket_cursor, NB);
    k_bscatter<<<256, blk, 0, stream>>>(row, col, E, bucket_cursor, pairbuf, NB);
    k_bcsr<<<NB, blk, 0, stream>>>(pairbuf, bucket_base, rowptr, cnt, dinv, csr, N);

    // layer 1: fp32 x -> fp16 lin (unscaled) -> weighted gather -> fp16 h1
    k_gemm<128, false, false, true><<<gemm_blocks, blk, 0, stream>>>(x, W1, dinv, bufA, N);
    k_gather_q<true, true><<<node_blocks, blk, 0, stream>>>(bufA, csr, rowptr, cnt, dinv, b1, bufB, N);
    // layer 2: fp16 h1 -> fp16 linS (pre-scaled) -> gather -> fp16 h2
    k_gemm<64, true, true, true><<<gemm_blocks, blk, 0, stream>>>(bufB, W2, dinv, bufA, N);
    k_gather_q<false, true><<<node_blocks, blk, 0, stream>>>(bufA, csr, rowptr, cnt, dinv, b2, bufB, N);
    // layer 3: fp16 h2 -> fp16 linS -> gather -> fp32 node_emb (output)
    k_gemm<64, true, true, true><<<gemm_blocks, blk, 0, stream>>>(bufB, W3, dinv, bufA, N);
    k_gather_q<false, false><<<node_blocks, blk, 0, stream>>>(bufA, csr, rowptr, cnt, dinv, b3, node_emb, N);

    // pool + classifier
    k_pool<<<pool_blocks, blk, 0, stream>>>(node_emb, batch, sums, cnts, N);
    k_final2<<<G, dim3(64), 0, stream>>>(sums, cnts, Wm, bm, logits, probs, graph_emb);
}